// Round 17
// baseline (560.115 us; speedup 1.0000x reference)
//
#include <hip/hip_runtime.h>
#include <math.h>

#define N_ENT   100000
#define N_REL2  1000
#define E_TOT   500000
#define E_HALF  250000
#define DIM     200
#define BB      256
#define NFILT   200
#define FLATK   39200
#define EPS_BN  1e-5f

#define NROWS   200000          // 100k in-rows + 100k out-rows
#define SCHUNK  2048
#define SNBLK   ((NROWS + SCHUNK - 1) / SCHUNK)   // 98

#define FC_KC   175             // fc split-K chunks (39200 = 175 * 224)
#define FC_KLEN 224             // 7 mfma k-steps

typedef __attribute__((ext_vector_type(8))) short bf16x8;   // 8 bf16 (4 VGPRs)
typedef __attribute__((ext_vector_type(4))) float f32x4;

#define GLOBAL_AS __attribute__((address_space(1)))
#define LDS_AS    __attribute__((address_space(3)))

__device__ __forceinline__ unsigned short f2b(float f) {
    union { float f; unsigned u; } c; c.f = f;
    unsigned u = c.u;
    u += 0x7fffu + ((u >> 16) & 1u);          // round-to-nearest-even
    return (unsigned short)(u >> 16);
}
__device__ __forceinline__ float b2f(unsigned short h) {
    union { unsigned u; float f; } c; c.u = ((unsigned)h) << 16;
    return c.f;
}
__device__ __forceinline__ float fast_tanh(float x) {
    float ax = fabsf(x);
    float e = __expf(-2.0f * ax);             // in (0,1], never overflows
    float t = (1.0f - e) / (1.0f + e);
    return copysignf(t, x);
}

// ---------------------------------------------------------------------------
// fused fp32 -> bf16 convert for two arrays (one launch)
// ---------------------------------------------------------------------------
__global__ void convert2_kernel(const float* __restrict__ s1, unsigned short* __restrict__ d1,
                                int n1, const float* __restrict__ s2,
                                unsigned short* __restrict__ d2, int n2, int nb1) {
    int b = blockIdx.x;
    const float* s; unsigned short* d; int n, base;
    if (b < nb1) { s = s1; d = d1; n = n1; base = b; }
    else         { s = s2; d = d2; n = n2; base = b - nb1; }
    int i = (base * 256 + threadIdx.x) * 4;
    if (i + 3 < n) {
        float4 v = *(const float4*)(s + i);
        ushort4 o;
        o.x = f2b(v.x); o.y = f2b(v.y); o.z = f2b(v.z); o.w = f2b(v.w);
        *(ushort4*)(d + i) = o;
    } else {
        for (; i < n; ++i) d[i] = f2b(s[i]);
    }
}

// ---------------------------------------------------------------------------
// Build WTK (k-major weights) + lv = loop_rel @ w_loop, fused.
// ---------------------------------------------------------------------------
__global__ void wstack_lv_kernel(const float* __restrict__ wIn, const float* __restrict__ wOut,
                                 const float* __restrict__ wLoop,
                                 const float* __restrict__ lr, float* __restrict__ lv,
                                 unsigned short* __restrict__ WTK) {
    if (blockIdx.x == 588) {
        int j = threadIdx.x;
        if (j < DIM) {
            float acc = 0.f;
            for (int k = 0; k < DIM; ++k) acc += lr[k] * wLoop[k * DIM + j];
            lv[j] = acc;
        }
        return;
    }
    int g = blockIdx.x * 256 + threadIdx.x;
    int kk = g & 7;
    int t = g >> 3;
    int col = t % 224;
    int t2 = t / 224;
    int unit = t2 % 28;
    int seg = t2 / 28;
    int k = unit * 8 + kk;
    float v = 0.f;
    if (col < 200 && k < 200)
        v = (seg == 0 ? wIn : seg == 1 ? wOut : wLoop)[k * 200 + col];
    WTK[g] = f2b(v);
}

// ---------------------------------------------------------------------------
// fc weight transpose (blocks 0..8574) + CWT build (blocks 8575..8626), fused.
// ---------------------------------------------------------------------------
__global__ void fwt_cwt_kernel(const float* __restrict__ fw, unsigned short* __restrict__ FWT,
                               const float* __restrict__ cw, unsigned short* __restrict__ CWT) {
    __shared__ float t[32][33];
    const int bid = blockIdx.x;
    const int tid = threadIdx.x;
    if (bid >= 8575) {
        int g = (bid - 8575) * 256 + tid;   // < 13312
        int f = g >> 6, k = g & 63;
        CWT[g] = (f < 200 && k < 49) ? f2b(cw[f * 49 + k]) : 0;
        return;
    }
    const int kt = bid % 1225, jt = bid / 1225;
#pragma unroll
    for (int it = 0; it < 4; ++it) {
        int idx = tid + it * 256;
        int kk = idx >> 5, jj = idx & 31;
        int j = jt * 32 + jj;
        t[kk][jj] = (j < 200) ? fw[(size_t)(kt * 32 + kk) * 200 + j] : 0.f;
    }
    __syncthreads();
#pragma unroll
    for (int it = 0; it < 4; ++it) {
        int idx = tid + it * 256;
        int jj = idx >> 5, kk = idx & 31;
        int j = jt * 32 + jj;
        if (j < 208)
            FWT[(size_t)j * FLATK + kt * 32 + kk] = f2b(t[kk][jj]);
    }
}

// ---------------------------------------------------------------------------
// CSR build
// ---------------------------------------------------------------------------
__global__ void hist_kernel(const int* __restrict__ ei, int* __restrict__ cnt) {
    int e = blockIdx.x * 256 + threadIdx.x;
    if (e >= E_TOT) return;
    int row = ei[E_TOT + e] + (e < E_HALF ? 0 : N_ENT);
    atomicAdd(&cnt[row], 1);
}

__global__ void scan1_kernel(const int* __restrict__ cnt, int* __restrict__ row_start,
                             int* __restrict__ blockSum) {
    __shared__ int tsum[256];
    const int t = threadIdx.x;
    const int base = blockIdx.x * SCHUNK + t * 8;
    int v[8];
    int s = 0;
#pragma unroll
    for (int i = 0; i < 8; ++i) {
        int idx = base + i;
        int c = (idx < NROWS) ? cnt[idx] : 0;
        v[i] = s;
        s += c;
    }
    tsum[t] = s;
    __syncthreads();
    for (int off = 1; off < 256; off <<= 1) {
        int x = (t >= off) ? tsum[t - off] : 0;
        __syncthreads();
        if (t >= off) tsum[t] += x;
        __syncthreads();
    }
    int texc = (t == 0) ? 0 : tsum[t - 1];
    if (t == 0) blockSum[blockIdx.x] = tsum[255];
#pragma unroll
    for (int i = 0; i < 8; ++i) {
        int idx = base + i;
        if (idx < NROWS) row_start[idx] = texc + v[i];
    }
}

// parallel exclusive scan over the 98 block sums (single 128-thread block)
__global__ void scan2_kernel(int* __restrict__ blockSum) {
    __shared__ int t[128];
    int i = threadIdx.x;
    int v = (i < SNBLK) ? blockSum[i] : 0;
    t[i] = v;
    __syncthreads();
    for (int off = 1; off < 128; off <<= 1) {
        int x = (i >= off) ? t[i - off] : 0;
        __syncthreads();
        t[i] += x;
        __syncthreads();
    }
    if (i < SNBLK) blockSum[i] = (i == 0) ? 0 : t[i - 1];
}

__global__ void scan3_kernel(int* __restrict__ row_start, int* __restrict__ row_cur,
                             const int* __restrict__ blockSum) {
    int i = blockIdx.x * 256 + threadIdx.x;
    if (i >= NROWS) return;
    int v = row_start[i] + blockSum[i / SCHUNK];
    row_start[i] = v;
    row_cur[i] = v;
}

__global__ void fill_kernel(const int* __restrict__ ei, const int* __restrict__ et,
                            int* __restrict__ row_cur, int2* __restrict__ epair) {
    int e = blockIdx.x * 256 + threadIdx.x;
    if (e >= E_TOT) return;
    int row = ei[E_TOT + e] + (e < E_HALF ? 0 : N_ENT);
    int pos = atomicAdd(&row_cur[row], 1);
    epair[pos] = make_int2(ei[e], et[e]);
}

// ---------------------------------------------------------------------------
// gather (bf16): one wave per CSR row, lanes 0..49 own 4 bf16 each; fp32 accum;
// degree loop unrolled x2 with dual accumulators to break the latency chain.
// ---------------------------------------------------------------------------
__global__ void gather_kernel(const unsigned short* __restrict__ x,
                              const unsigned short* __restrict__ r,
                              const int2* __restrict__ epair,
                              const int* __restrict__ row_start, const int* __restrict__ cnt,
                              unsigned short* __restrict__ agg) {
    int wid = blockIdx.x * 4 + (threadIdx.x >> 6);
    if (wid >= NROWS) return;
    int lane = threadIdx.x & 63;
    if (lane >= 50) return;
    int start = row_start[wid];
    int deg = cnt[wid];
    float a0 = 0.f, a1 = 0.f, a2 = 0.f, a3 = 0.f;
    float c0 = 0.f, c1 = 0.f, c2 = 0.f, c3 = 0.f;
    int i = 0;
    for (; i + 2 <= deg; i += 2) {
        int2 e0 = epair[start + i];
        int2 e1 = epair[start + i + 1];
        ushort4 xv0 = *(const ushort4*)(x + (size_t)e0.x * DIM + lane * 4);
        ushort4 rv0 = *(const ushort4*)(r + (size_t)e0.y * DIM + lane * 4);
        ushort4 xv1 = *(const ushort4*)(x + (size_t)e1.x * DIM + lane * 4);
        ushort4 rv1 = *(const ushort4*)(r + (size_t)e1.y * DIM + lane * 4);
        a0 += b2f(xv0.x) - b2f(rv0.x);
        a1 += b2f(xv0.y) - b2f(rv0.y);
        a2 += b2f(xv0.z) - b2f(rv0.z);
        a3 += b2f(xv0.w) - b2f(rv0.w);
        c0 += b2f(xv1.x) - b2f(rv1.x);
        c1 += b2f(xv1.y) - b2f(rv1.y);
        c2 += b2f(xv1.z) - b2f(rv1.z);
        c3 += b2f(xv1.w) - b2f(rv1.w);
    }
    if (i < deg) {
        int2 e = epair[start + i];
        ushort4 xv = *(const ushort4*)(x + (size_t)e.x * DIM + lane * 4);
        ushort4 rv = *(const ushort4*)(r + (size_t)e.y * DIM + lane * 4);
        a0 += b2f(xv.x) - b2f(rv.x);
        a1 += b2f(xv.y) - b2f(rv.y);
        a2 += b2f(xv.z) - b2f(rv.z);
        a3 += b2f(xv.w) - b2f(rv.w);
    }
    float sc = 1.0f / fmaxf((float)deg, 1.0f);
    ushort4 o;
    o.x = f2b((a0 + c0) * sc);
    o.y = f2b((a1 + c1) * sc);
    o.z = f2b((a2 + c2) * sc);
    o.w = f2b((a3 + c3) * sc);
    *(ushort4*)(agg + (size_t)wid * DIM + lane * 4) = o;
}

// ---------------------------------------------------------------------------
// r_out = r_in @ w   fp32 (+ optional bf16 copy), tiny (rows=1000)
// ---------------------------------------------------------------------------
__global__ void rgemm_kernel(const float* __restrict__ r, const float* __restrict__ w,
                             float* __restrict__ out, unsigned short* __restrict__ outb,
                             int rows) {
    int g = blockIdx.x * 256 + threadIdx.x;
    if (g >= rows * DIM) return;
    int i = g / DIM, j = g - i * DIM;
    float acc = 0.f;
    for (int k = 0; k < DIM; ++k) acc += r[i * DIM + k] * w[k * DIM + j];
    out[g] = acc;
    if (outb) outb[g] = f2b(acc);
}

// ---------------------------------------------------------------------------
// MFMA layer v10 = R12 structure with global_load_lds staging: the k-major
// LDS destination is linear in lane order (thread u -> Wl + u*16B), exactly
// the wave-uniform-base + lane*16 layout gload_lds requires. Removes the
// reg round-trip: no ds_writes (26% of the block's LDS-pipe traffic), no
// vals[] registers, one address-calc pass. Async loads issued at phase top
// land under the end-of-phase barrier's vmcnt drain (same hazard structure
// as the reg-staged T14 schedule). Slice 10's tail chunk (g2=21) is never
// issued and never read (NC=1).
// ---------------------------------------------------------------------------
#define LOAD_A1(g, slot) do {                                                   \
    const unsigned short* Ap_ = Aseg[(g) / 7];                                  \
    apf[slot] = *(const bf16x8*)(Ap_ + (size_t)arow * 200 + ((g) % 7) * 32 + lq * 8); \
} while (0)

// async-stage slice s (chunks 2s, 2s+1) into LDS buffer b via global_load_lds
#define STAGE_GLD(s, b) do {                                                     \
    _Pragma("unroll")                                                            \
    for (int it = 0; it < 4; ++it) {                                             \
        int u = tid + it * 256;                                                  \
        int slot = u / 448;                                                      \
        int rem  = u - slot * 448;                                               \
        int ui   = rem / 112, col = rem - ui * 112;                              \
        int g2   = (s) * 2 + slot;                                               \
        if (u < 896 && g2 < 21) {                                                \
            int sg = g2 / 7, kc = g2 % 7;                                        \
            const unsigned short* gp = WTK +                                     \
                ((size_t)(sg * 28 + kc * 4 + ui) * 224 + colbase + col) * 8;     \
            __builtin_amdgcn_global_load_lds(                                    \
                (const GLOBAL_AS unsigned int*)(const void*)gp,                  \
                (LDS_AS unsigned int*)(void*)(&Wl[(b)][u * 8]), 16, 0, 0);       \
        }                                                                        \
    }                                                                            \
} while (0)

__global__ __launch_bounds__(256, 4) void layer_mfma_kernel(
        const unsigned short* __restrict__ aggI, const unsigned short* __restrict__ aggO,
        const unsigned short* __restrict__ xin, const unsigned short* __restrict__ WTK,
        const float* __restrict__ lv, const float* __restrict__ bias,
        unsigned short* __restrict__ out, int nwg) {
    __shared__ unsigned short Wl[2][8 * 112 * 8];     // 2 x 14,336 B
    const int bid = blockIdx.x;
    const int q = nwg >> 3, rr = nwg & 7;
    const int xcd = bid & 7, idx = bid >> 3;
    const int L = (xcd < rr ? xcd * (q + 1) : rr * (q + 1) + (xcd - rr) * q) + idx;
    const int rowblk  = L >> 1;
    const int colbase = (L & 1) * 112;

    const int tid  = threadIdx.x;
    const int wm   = tid >> 6;
    const int lane = tid & 63;
    const int lr   = lane & 15;
    const int lq   = lane >> 4;
    const int row0 = rowblk * 64;
    const int arow = row0 + wm * 16 + lr;

    const unsigned short* const Aseg[3] = { aggI, aggO, xin };

    f32x4 acc[7];
#pragma unroll
    for (int n = 0; n < 7; ++n) acc[n] = (f32x4){0.f, 0.f, 0.f, 0.f};

    bf16x8 apf[4];                        // rotating A prefetch, depth 3
    LOAD_A1(0, 0);
    LOAD_A1(1, 1);
    LOAD_A1(2, 2);

    // prologue: async-stage slice 0 into buf 0 (vmcnt drained at barrier)
    STAGE_GLD(0, 0);
    __syncthreads();

#pragma unroll
    for (int p = 0; p < 11; ++p) {
        // issue next slice's async loads first (latency hides under compute)
        if (p < 10) STAGE_GLD(p + 1, (p + 1) & 1);
        const int NC = (p < 10) ? 2 : 1;
#pragma unroll
        for (int cc = 0; cc < NC; ++cc) {
            const int g = p * 2 + cc;                 // literal after unroll
            if (g + 3 < 21) LOAD_A1(g + 3, (g + 3) & 3);
            __builtin_amdgcn_s_setprio(1);
#pragma unroll
            for (int n = 0; n < 7; ++n) {
                bf16x8 b = *(const bf16x8*)(&Wl[p & 1][((cc * 4 + lq) * 112 + n * 16 + lr) * 8]);
                acc[n] = __builtin_amdgcn_mfma_f32_16x16x32_bf16(apf[g & 3], b, acc[n], 0, 0, 0);
            }
            __builtin_amdgcn_s_setprio(0);
        }
        __syncthreads();                  // drains vmcnt: slice p+1 landed
    }

    {
        int rbase = row0 + wm * 16 + lq * 4;
#pragma unroll
        for (int n = 0; n < 7; ++n) {
            int col = colbase + n * 16 + lr;
            if (col < 200) {
                float lvc = lv[col], bc = bias[col];
#pragma unroll
                for (int r2 = 0; r2 < 4; ++r2) {
                    int row = rbase + r2;
                    if (row < N_ENT) {
                        float v = (acc[n][r2] - lvc) * (1.0f / 3.0f) + bc;
                        out[(size_t)row * 200 + col] = f2b(fast_tanh(v));
                    }
                }
            }
        }
    }
}

// ---------------------------------------------------------------------------
// im2col fused with BN0 image build: IM[b*196+p][64] directly from x/r.
// k = i*7+j (49 real, 64 padded); value = BN0(stack(sub_emb, rel_emb)).
// ---------------------------------------------------------------------------
__global__ void im2col_kernel(const unsigned short* __restrict__ x, const float* __restrict__ r,
                              const int* __restrict__ sub, const int* __restrict__ rel,
                              const float* __restrict__ bn0g, const float* __restrict__ bn0b,
                              unsigned short* __restrict__ IM) {
    int g = blockIdx.x * 256 + threadIdx.x;
    if (g >= 50176 * 64) return;
    int row = g >> 6, k = g & 63;
    int b = row / 196, p = row - b * 196;
    int h = p / 14, w = p - h * 14;
    unsigned short o = 0;
    if (k < 49) {
        int i = k / 7, j = k - i * 7;
        int l = (h + i) * 20 + (w + j);
        int d = l >> 1;
        float v = (l & 1) ? r[(size_t)rel[b] * DIM + d] : b2f(x[(size_t)sub[b] * DIM + d]);
        float s0 = bn0g[0] * rsqrtf(1.0f + EPS_BN);
        o = f2b(v * s0 + bn0b[0]);
    }
    IM[g] = o;
}

// ---------------------------------------------------------------------------
// conv as MFMA: [50176 x 64] @ [64 x 200(pad 208)], zero-LDS/zero-barrier.
// ---------------------------------------------------------------------------
__global__ __launch_bounds__(256) void conv_mfma_kernel(
        const unsigned short* __restrict__ IM, const unsigned short* __restrict__ CWT,
        const float* __restrict__ cb, const float* __restrict__ bn1g,
        const float* __restrict__ bn1b, unsigned short* __restrict__ CO_B) {
    const int tid  = threadIdx.x;
    const int row0 = blockIdx.x * 128;
    const int wave = tid >> 6;
    const int lane = tid & 63;
    const int lr   = lane & 15;
    const int lq   = lane >> 4;
    const int arow = row0 + wave * 32 + lr;

    f32x4 acc[2][13];
#pragma unroll
    for (int m = 0; m < 2; ++m)
#pragma unroll
        for (int n = 0; n < 13; ++n) acc[m][n] = (f32x4){0.f, 0.f, 0.f, 0.f};

#pragma unroll
    for (int c = 0; c < 2; ++c) {
        const int k = c * 32 + lq * 8;
        bf16x8 a0 = *(const bf16x8*)(IM + (size_t)arow * 64 + k);
        bf16x8 a1 = *(const bf16x8*)(IM + (size_t)(arow + 16) * 64 + k);
#pragma unroll
        for (int n = 0; n < 13; ++n) {
            bf16x8 b = *(const bf16x8*)(CWT + (size_t)(n * 16 + lr) * 64 + k);
            acc[0][n] = __builtin_amdgcn_mfma_f32_16x16x32_bf16(a0, b, acc[0][n], 0, 0, 0);
            acc[1][n] = __builtin_amdgcn_mfma_f32_16x16x32_bf16(a1, b, acc[1][n], 0, 0, 0);
        }
    }

#pragma unroll
    for (int m = 0; m < 2; ++m) {
        int grow_base = row0 + wave * 32 + m * 16 + lq * 4;
#pragma unroll
        for (int n = 0; n < 13; ++n) {
            int col = n * 16 + lr;          // filter
            if (col < 200) {
                float s1 = bn1g[col] * rsqrtf(1.0f + EPS_BN);
                float t1 = bn1b[col];
                float cbf = cb[col];
#pragma unroll
                for (int r = 0; r < 4; ++r) {
                    int grow = grow_base + r;          // b*196+p, always < 50176
                    int b = grow / 196, p = grow - b * 196;
                    float v = fmaxf((acc[m][n][r] + cbf) * s1 + t1, 0.f);
                    CO_B[(size_t)b * FLATK + col * 196 + p] = f2b(v);
                }
            }
        }
    }
}

// ---------------------------------------------------------------------------
// fc as MFMA split-K: [256 x 39200] @ [39200 x 208], 175 k-chunks x 4 m-blocks.
// ---------------------------------------------------------------------------
__global__ __launch_bounds__(256) void fc_mfma_kernel(
        const unsigned short* __restrict__ CO_B, const unsigned short* __restrict__ FWT,
        float* __restrict__ partials) {
    const int tid  = threadIdx.x;
    const int kc   = blockIdx.x >> 2;
    const int mb   = blockIdx.x & 3;
    const int wave = tid >> 6;
    const int lane = tid & 63;
    const int lr   = lane & 15;
    const int lq   = lane >> 4;
    const int m0   = mb * 64 + wave * 16;

    f32x4 acc[13];
#pragma unroll
    for (int n = 0; n < 13; ++n) acc[n] = (f32x4){0.f, 0.f, 0.f, 0.f};

#pragma unroll
    for (int s = 0; s < 7; ++s) {
        const int k = kc * FC_KLEN + s * 32 + lq * 8;
        bf16x8 a = *(const bf16x8*)(CO_B + (size_t)(m0 + lr) * FLATK + k);
#pragma unroll
        for (int n = 0; n < 13; ++n) {
            bf16x8 b = *(const bf16x8*)(FWT + (size_t)(n * 16 + lr) * FLATK + k);
            acc[n] = __builtin_amdgcn_mfma_f32_16x16x32_bf16(a, b, acc[n], 0, 0, 0);
        }
    }

    float* slab = partials + (size_t)kc * (BB * 208);
#pragma unroll
    for (int n = 0; n < 13; ++n) {
        int col = n * 16 + lr;
#pragma unroll
        for (int r = 0; r < 4; ++r) {
            int row = m0 + lq * 4 + r;
            slab[(size_t)row * 208 + col] = acc[n][r];
        }
    }
}

// hb16[b][j=224] = relu((sum_kc partial + fc_b)*bn2s+bn2b) bf16, pad j>=200
__global__ void fc_reduce_kernel(const float* __restrict__ partials,
                                 const float* __restrict__ fcb,
                                 const float* __restrict__ g2, const float* __restrict__ b2v,
                                 unsigned short* __restrict__ hb) {
    int g = blockIdx.x * 256 + threadIdx.x;
    if (g >= BB * 224) return;
    int b = g / 224, j = g - b * 224;
    unsigned short o = 0;
    if (j < 200) {
        float s = 0.f;
        const float* p = partials + (size_t)b * 208 + j;
#pragma unroll 5
        for (int c = 0; c < FC_KC; ++c)
            s += p[(size_t)c * (BB * 208)];
        float v = (s + fcb[j]) * (g2[j] * rsqrtf(1.0f + EPS_BN)) + b2v[j];
        o = f2b(fmaxf(v, 0.f));
    }
    hb[g] = o;
}

// ---------------------------------------------------------------------------
// logits MFMA v2: D[b][ent] = sigmoid(h[b]·x[ent] + eb[ent]).
// ---------------------------------------------------------------------------
#define LOAD_HB(g, buf) do {                                                    \
    const unsigned short* base_ = hb + (size_t)brow * 224 + (g) * 32 + lq * 8;  \
    buf[0] = *(const bf16x8*)(base_);                                           \
    buf[1] = *(const bf16x8*)(base_ + 16 * 224);                                \
} while (0)

__global__ __launch_bounds__(512, 2) void logits_mfma_kernel(
        const unsigned short* __restrict__ x, const unsigned short* __restrict__ hb,
        const float* __restrict__ eb, float* __restrict__ out, int nwg) {
    __shared__ unsigned short Xl[112 * 136];          // 30,464 B
    const int bid = blockIdx.x;
    const int q = nwg >> 3, rr = nwg & 7;
    const int xcd = bid & 7, idx = bid >> 3;
    const int nb = (xcd < rr ? xcd * (q + 1) : rr * (q + 1) + (xcd - rr) * q) + idx;
    const int ent0 = nb * 112;

    const int tid  = threadIdx.x;
    const int wave = tid >> 6;
    const int mh   = wave >> 2;          // batch half (0/1)
    const int wm   = wave & 3;           // 32-row group
    const int lane = tid & 63;
    const int lr   = lane & 15;
    const int lq   = lane >> 4;
    const int brow = mh * 128 + wm * 32 + lr;

    f32x4 acc[2][7];
#pragma unroll
    for (int m = 0; m < 2; ++m)
#pragma unroll
        for (int n = 0; n < 7; ++n) acc[m][n] = (f32x4){0.f, 0.f, 0.f, 0.f};

    bf16x8 apf[3][2];                     // rotating A prefetch, depth 2
    LOAD_HB(0, apf[0]);
    LOAD_HB(1, apf[1]);

#pragma unroll
    for (int ph = 0; ph < 2; ++ph) {
        if (ph) __syncthreads();
        if (ph == 0) {
            // stage k 0..127: 112 rows x 16 int4 units (contiguous per row)
#pragma unroll
            for (int it = 0; it < 4; ++it) {
                int u = tid + it * 512;
                if (u < 1792) {
                    int row = u >> 4, c = u & 15;
                    int ent = ent0 + row;
                    int4 v = make_int4(0, 0, 0, 0);
                    if (ent < N_ENT)
                        v = *(const int4*)(x + (size_t)ent * 200 + c * 8);
                    *(int4*)(&Xl[row * 136 + c * 8]) = v;
                }
            }
        } else {
            // stage k 128..223: units 16..27 (real to unit 24, then zeros)
            for (int u = tid; u < 1344; u += 512) {
                int row = u / 12, c = u - row * 12;
                int gu = 16 + c;
                int ent = ent0 + row;
                int4 v = make_int4(0, 0, 0, 0);
                if (ent < N_ENT && gu < 25)
                    v = *(const int4*)(x + (size_t)ent * 200 + gu * 8);
                *(int4*)(&Xl[row * 136 + c * 8]) = v;
            }
        }
        __syncthreads();
        const int NC = (ph == 0) ? 4 : 3;
#pragma unroll
        for (int cc = 0; cc < NC; ++cc) {
            const int g = (ph ? 4 : 0) + cc;
            if (g + 2 < 7) LOAD_HB(g + 2, apf[(g + 2) % 3]);
#pragma unroll
            for (int n = 0; n < 7; ++n) {
                bf16x8 b = *(const bf16x8*)(&Xl[(n * 16 + lr) * 136 + cc * 32 + lq * 8]);
                acc[0][n] = __builtin_amdgcn_mfma_f32_16x16x32_bf16(apf[g % 3][0], b, acc[0][n], 0, 0, 0);
                acc[1][n] = __builtin_amdgcn_mfma_f32_16x16x32_bf16(apf[g % 3][1], b, acc[1][n], 0, 0, 0);
            }
        }
    }

#pragma unroll
    for (int m = 0; m < 2; ++m) {
        int b_base = mh * 128 + wm * 32 + m * 16 + lq * 4;
#pragma unroll
        for (int n = 0; n < 7; ++n) {
            int ent = ent0 + n * 16 + lr;
            if (ent < N_ENT) {
                float bias = eb[ent];
#pragma unroll
                for (int r = 0; r < 4; ++r) {
                    float v = acc[m][n][r] + bias;
                    out[(size_t)(b_base + r) * N_ENT + ent] = 1.0f / (1.0f + __expf(-v));
                }
            }
        }
    }
}

// ---------------------------------------------------------------------------
extern "C" void kernel_launch(void* const* d_in, const int* in_sizes, int n_in,
                              void* d_out, int out_size, void* d_ws, size_t ws_size,
                              hipStream_t stream) {
    const int*   sub        = (const int*)  d_in[0];
    const int*   rel        = (const int*)  d_in[1];
    const int*   edge_index = (const int*)  d_in[2];
    const int*   edge_type  = (const int*)  d_in[3];
    const float* init_embed = (const float*)d_in[4];
    const float* init_rel   = (const float*)d_in[5];
    const float* loop_rel1  = (const float*)d_in[6];
    const float* loop_rel2  = (const float*)d_in[7];
    const float* w_in1      = (const float*)d_in[8];
    const float* w_out1     = (const float*)d_in[9];
    const float* w_loop1    = (const float*)d_in[10];
    const float* w_rel1     = (const float*)d_in[11];
    const float* b1         = (const float*)d_in[12];
    const float* w_in2      = (const float*)d_in[13];
    const float* w_out2     = (const float*)d_in[14];
    const float* w_loop2    = (const float*)d_in[15];
    const float* w_rel2     = (const float*)d_in[16];
    const float* b2         = (const float*)d_in[17];
    const float* conv_w     = (const float*)d_in[18];
    const float* conv_b     = (const float*)d_in[19];
    const float* bn0_g      = (const float*)d_in[20];
    const float* bn0_b      = (const float*)d_in[21];
    const float* bn1_g      = (const float*)d_in[22];
    const float* bn1_b      = (const float*)d_in[23];
    const float* bn2_g      = (const float*)d_in[24];
    const float* bn2_b      = (const float*)d_in[25];
    const float* fc_w       = (const float*)d_in[26];
    const float* fc_b       = (const float*)d_in[27];
    const float* ent_bias   = (const float*)d_in[28];

    // ---- bf16 region ----
    unsigned short* aggb = (unsigned short*)d_ws;     // 40,000,000
    unsigned short* x0b  = aggb + 40000000;           // 20,000,000 (init; reused as x2b)
    unsigned short* x1b  = x0b  + 20000000;           // 20,000,000
    unsigned short* r0b  = x1b  + 20000000;           //    200,000
    unsigned short* r1b  = r0b  + 200000;             //    200,000
    unsigned short* WTK  = r1b  + 200000;             //    150,528 (3*28*224*8)
    unsigned short* img  = WTK  + 150528;             //    102,400 (unused, kept for layout)
    unsigned short* IM   = img  + 102400;             //  3,211,264 (50176*64)
    unsigned short* CWT  = IM   + 3211264;            //     13,312
    unsigned short* CO_B = CWT  + 13312;              // 10,035,200 (256*39200)
    unsigned short* hb16 = CO_B + 10035200;           //     57,344 (256*224)
    unsigned short* FWT  = hb16 + 57344;              //  8,153,600 (208*39200)
    // ---- fp32 region ----
    float* fbase = (float*)(FWT + 8153600);
    float* r1f      = fbase;                          // 200,000
    float* r2f      = r1f  + 200000;                  // 200,000
    float* lv       = r2f  + 200000;                  // 256
    float* partials = lv   + 256;                     // 9,318,400 (175*256*208)

    // CSR ints alias CO_B (last CSR read = gather2, before conv writes CO_B)
    int2* epair    = (int2*)CO_B;                     // 500,000 int2
    int* cnt       = (int*)(epair + E_TOT);           // 200,000
    int* row_start = cnt  + NROWS;                    // 200,000
    int* row_cur   = row_start + NROWS;               // 200,000
    int* blockSum  = row_cur + NROWS;                 // 98

    unsigned short* aggIb = aggb;
    unsigned short* aggOb = aggb + (size_t)N_ENT * DIM;
    unsigned short* x2b   = x0b;

    const int gather_blocks = (NROWS + 3) / 4;
    const int layer_nwg     = ((N_ENT + 63) / 64) * 2;     // 3126 (64-row x 2 col-halves)
    const int logits_nwg    = (N_ENT + 111) / 112;         // 893
    const int cvt_nb1       = (N_ENT * DIM / 4 + 255) / 256;   // 19532
    const int cvt_nb2       = (N_REL2 * DIM / 4 + 255) / 256;  // 196

    // ---- converts (fused) + CSR build ----
    convert2_kernel<<<cvt_nb1 + cvt_nb2, 256, 0, stream>>>(init_embed, x0b, N_ENT * DIM,
                                                           init_rel, r0b, N_REL2 * DIM, cvt_nb1);
    hipMemsetAsync(cnt, 0, (size_t)NROWS * 4, stream);
    hist_kernel<<<(E_TOT + 255) / 256, 256, 0, stream>>>(edge_index, cnt);
    scan1_kernel<<<SNBLK, 256, 0, stream>>>(cnt, row_start, blockSum);
    scan2_kernel<<<1, 128, 0, stream>>>(blockSum);
    scan3_kernel<<<(NROWS + 255) / 256, 256, 0, stream>>>(row_start, row_cur, blockSum);
    fill_kernel<<<(E_TOT + 255) / 256, 256, 0, stream>>>(edge_index, edge_type, row_cur, epair);

    // ---- layer 1 ----
    wstack_lv_kernel<<<589, 256, 0, stream>>>(w_in1, w_out1, w_loop1, loop_rel1, lv, WTK);
    gather_kernel<<<gather_blocks, 256, 0, stream>>>(x0b, r0b, epair, row_start, cnt, aggb);
    layer_mfma_kernel<<<layer_nwg, 256, 0, stream>>>(aggIb, aggOb, x0b, WTK, lv, b1, x1b, layer_nwg);
    rgemm_kernel<<<(N_REL2 * DIM + 255) / 256, 256, 0, stream>>>(init_rel, w_rel1, r1f, r1b, N_REL2);

    // ---- layer 2 ----
    wstack_lv_kernel<<<589, 256, 0, stream>>>(w_in2, w_out2, w_loop2, loop_rel2, lv, WTK);
    gather_kernel<<<gather_blocks, 256, 0, stream>>>(x1b, r1b, epair, row_start, cnt, aggb);
    layer_mfma_kernel<<<layer_nwg, 256, 0, stream>>>(aggIb, aggOb, x1b, WTK, lv, b2, x2b, layer_nwg);
    rgemm_kernel<<<(N_REL2 * DIM + 255) / 256, 256, 0, stream>>>(r1f, w_rel2, r2f,
                                                                 (unsigned short*)nullptr, N_REL2);

    // ---- ConvE ----
    im2col_kernel<<<(50176 * 64 + 255) / 256, 256, 0, stream>>>(x2b, r2f, sub, rel,
                                                                bn0_g, bn0_b, IM);
    fwt_cwt_kernel<<<8575 + 52, 256, 0, stream>>>(fc_w, FWT, conv_w, CWT);
    conv_mfma_kernel<<<50176 / 128, 256, 0, stream>>>(IM, CWT, conv_b, bn1_g, bn1_b, CO_B);
    fc_mfma_kernel<<<FC_KC * 4, 256, 0, stream>>>(CO_B, FWT, partials);
    fc_reduce_kernel<<<(BB * 224 + 255) / 256, 256, 0, stream>>>(partials, fc_b, bn2_g, bn2_b, hb16);

    // ---- logits ----
    logits_mfma_kernel<<<logits_nwg, 512, 0, stream>>>(x2b, hb16, ent_bias, (float*)d_out,
                                                       logits_nwg);
}

// Round 18
// 544.363 us; speedup vs baseline: 1.0289x; 1.0289x over previous
//
#include <hip/hip_runtime.h>
#include <math.h>

#define N_ENT   100000
#define N_REL2  1000
#define E_TOT   500000
#define E_HALF  250000
#define DIM     200
#define BB      256
#define NFILT   200
#define FLATK   39200
#define EPS_BN  1e-5f

#define NROWS   200000          // 100k in-rows + 100k out-rows
#define SCHUNK  2048
#define SNBLK   ((NROWS + SCHUNK - 1) / SCHUNK)   // 98

#define FC_KC   175             // fc split-K chunks (39200 = 175 * 224)
#define FC_KLEN 224             // 7 mfma k-steps

typedef __attribute__((ext_vector_type(8))) short bf16x8;   // 8 bf16 (4 VGPRs)
typedef __attribute__((ext_vector_type(4))) float f32x4;

#define GLOBAL_AS __attribute__((address_space(1)))
#define LDS_AS    __attribute__((address_space(3)))

__device__ __forceinline__ unsigned short f2b(float f) {
    union { float f; unsigned u; } c; c.f = f;
    unsigned u = c.u;
    u += 0x7fffu + ((u >> 16) & 1u);          // round-to-nearest-even
    return (unsigned short)(u >> 16);
}
__device__ __forceinline__ float b2f(unsigned short h) {
    union { unsigned u; float f; } c; c.u = ((unsigned)h) << 16;
    return c.f;
}
__device__ __forceinline__ float fast_tanh(float x) {
    float ax = fabsf(x);
    float e = __expf(-2.0f * ax);             // in (0,1], never overflows
    float t = (1.0f - e) / (1.0f + e);
    return copysignf(t, x);
}

// ---------------------------------------------------------------------------
// fused fp32 -> bf16 convert for two arrays (one launch)
// ---------------------------------------------------------------------------
__global__ void convert2_kernel(const float* __restrict__ s1, unsigned short* __restrict__ d1,
                                int n1, const float* __restrict__ s2,
                                unsigned short* __restrict__ d2, int n2, int nb1) {
    int b = blockIdx.x;
    const float* s; unsigned short* d; int n, base;
    if (b < nb1) { s = s1; d = d1; n = n1; base = b; }
    else         { s = s2; d = d2; n = n2; base = b - nb1; }
    int i = (base * 256 + threadIdx.x) * 4;
    if (i + 3 < n) {
        float4 v = *(const float4*)(s + i);
        ushort4 o;
        o.x = f2b(v.x); o.y = f2b(v.y); o.z = f2b(v.z); o.w = f2b(v.w);
        *(ushort4*)(d + i) = o;
    } else {
        for (; i < n; ++i) d[i] = f2b(s[i]);
    }
}

// ---------------------------------------------------------------------------
// Build WTK (k-major weights) + lv = loop_rel @ w_loop, fused.
// ---------------------------------------------------------------------------
__global__ void wstack_lv_kernel(const float* __restrict__ wIn, const float* __restrict__ wOut,
                                 const float* __restrict__ wLoop,
                                 const float* __restrict__ lr, float* __restrict__ lv,
                                 unsigned short* __restrict__ WTK) {
    if (blockIdx.x == 588) {
        int j = threadIdx.x;
        if (j < DIM) {
            float acc = 0.f;
            for (int k = 0; k < DIM; ++k) acc += lr[k] * wLoop[k * DIM + j];
            lv[j] = acc;
        }
        return;
    }
    int g = blockIdx.x * 256 + threadIdx.x;
    int kk = g & 7;
    int t = g >> 3;
    int col = t % 224;
    int t2 = t / 224;
    int unit = t2 % 28;
    int seg = t2 / 28;
    int k = unit * 8 + kk;
    float v = 0.f;
    if (col < 200 && k < 200)
        v = (seg == 0 ? wIn : seg == 1 ? wOut : wLoop)[k * 200 + col];
    WTK[g] = f2b(v);
}

// ---------------------------------------------------------------------------
// fc weight transpose (blocks 0..8574) + CWT build (blocks 8575..8626), fused.
// ---------------------------------------------------------------------------
__global__ void fwt_cwt_kernel(const float* __restrict__ fw, unsigned short* __restrict__ FWT,
                               const float* __restrict__ cw, unsigned short* __restrict__ CWT) {
    __shared__ float t[32][33];
    const int bid = blockIdx.x;
    const int tid = threadIdx.x;
    if (bid >= 8575) {
        int g = (bid - 8575) * 256 + tid;   // < 13312
        int f = g >> 6, k = g & 63;
        CWT[g] = (f < 200 && k < 49) ? f2b(cw[f * 49 + k]) : 0;
        return;
    }
    const int kt = bid % 1225, jt = bid / 1225;
#pragma unroll
    for (int it = 0; it < 4; ++it) {
        int idx = tid + it * 256;
        int kk = idx >> 5, jj = idx & 31;
        int j = jt * 32 + jj;
        t[kk][jj] = (j < 200) ? fw[(size_t)(kt * 32 + kk) * 200 + j] : 0.f;
    }
    __syncthreads();
#pragma unroll
    for (int it = 0; it < 4; ++it) {
        int idx = tid + it * 256;
        int jj = idx >> 5, kk = idx & 31;
        int j = jt * 32 + jj;
        if (j < 208)
            FWT[(size_t)j * FLATK + kt * 32 + kk] = f2b(t[kk][jj]);
    }
}

// ---------------------------------------------------------------------------
// CSR build
// ---------------------------------------------------------------------------
__global__ void hist_kernel(const int* __restrict__ ei, int* __restrict__ cnt) {
    int e = blockIdx.x * 256 + threadIdx.x;
    if (e >= E_TOT) return;
    int row = ei[E_TOT + e] + (e < E_HALF ? 0 : N_ENT);
    atomicAdd(&cnt[row], 1);
}

__global__ void scan1_kernel(const int* __restrict__ cnt, int* __restrict__ row_start,
                             int* __restrict__ blockSum) {
    __shared__ int tsum[256];
    const int t = threadIdx.x;
    const int base = blockIdx.x * SCHUNK + t * 8;
    int v[8];
    int s = 0;
#pragma unroll
    for (int i = 0; i < 8; ++i) {
        int idx = base + i;
        int c = (idx < NROWS) ? cnt[idx] : 0;
        v[i] = s;
        s += c;
    }
    tsum[t] = s;
    __syncthreads();
    for (int off = 1; off < 256; off <<= 1) {
        int x = (t >= off) ? tsum[t - off] : 0;
        __syncthreads();
        if (t >= off) tsum[t] += x;
        __syncthreads();
    }
    int texc = (t == 0) ? 0 : tsum[t - 1];
    if (t == 0) blockSum[blockIdx.x] = tsum[255];
#pragma unroll
    for (int i = 0; i < 8; ++i) {
        int idx = base + i;
        if (idx < NROWS) row_start[idx] = texc + v[i];
    }
}

// parallel exclusive scan over the 98 block sums (single 128-thread block)
__global__ void scan2_kernel(int* __restrict__ blockSum) {
    __shared__ int t[128];
    int i = threadIdx.x;
    int v = (i < SNBLK) ? blockSum[i] : 0;
    t[i] = v;
    __syncthreads();
    for (int off = 1; off < 128; off <<= 1) {
        int x = (i >= off) ? t[i - off] : 0;
        __syncthreads();
        t[i] += x;
        __syncthreads();
    }
    if (i < SNBLK) blockSum[i] = (i == 0) ? 0 : t[i - 1];
}

__global__ void scan3_kernel(int* __restrict__ row_start, int* __restrict__ row_cur,
                             const int* __restrict__ blockSum) {
    int i = blockIdx.x * 256 + threadIdx.x;
    if (i >= NROWS) return;
    int v = row_start[i] + blockSum[i / SCHUNK];
    row_start[i] = v;
    row_cur[i] = v;
}

__global__ void fill_kernel(const int* __restrict__ ei, const int* __restrict__ et,
                            int* __restrict__ row_cur, int2* __restrict__ epair) {
    int e = blockIdx.x * 256 + threadIdx.x;
    if (e >= E_TOT) return;
    int row = ei[E_TOT + e] + (e < E_HALF ? 0 : N_ENT);
    int pos = atomicAdd(&row_cur[row], 1);
    epair[pos] = make_int2(ei[e], et[e]);
}

// ---------------------------------------------------------------------------
// gather v2 (bf16): one wave per CSR row, lanes 0..49 own 4 bf16 each.
// deg>=3 fast path: load 4 epairs up front, issue ALL 8 row loads
// concurrently (edge 3 predicated: clamped dup index, weight 0) — halves
// the serial dependent-chain depth for deg 3..4 rows (~46% of rows).
// Remaining edges fall through to the x2-unrolled loop.
// ---------------------------------------------------------------------------
__global__ void gather_kernel(const unsigned short* __restrict__ x,
                              const unsigned short* __restrict__ r,
                              const int2* __restrict__ epair,
                              const int* __restrict__ row_start, const int* __restrict__ cnt,
                              unsigned short* __restrict__ agg) {
    int wid = blockIdx.x * 4 + (threadIdx.x >> 6);
    if (wid >= NROWS) return;
    int lane = threadIdx.x & 63;
    if (lane >= 50) return;
    int start = row_start[wid];
    int deg = cnt[wid];
    float a0 = 0.f, a1 = 0.f, a2 = 0.f, a3 = 0.f;
    float c0 = 0.f, c1 = 0.f, c2 = 0.f, c3 = 0.f;
    int i = 0;
    if (deg >= 3) {
        int2 e0 = epair[start];
        int2 e1 = epair[start + 1];
        int2 e2 = epair[start + 2];
        int2 e3 = epair[start + ((deg >= 4) ? 3 : 2)];   // dup when deg==3
        float w3 = (deg >= 4) ? 1.0f : 0.0f;
        ushort4 xv0 = *(const ushort4*)(x + (size_t)e0.x * DIM + lane * 4);
        ushort4 rv0 = *(const ushort4*)(r + (size_t)e0.y * DIM + lane * 4);
        ushort4 xv1 = *(const ushort4*)(x + (size_t)e1.x * DIM + lane * 4);
        ushort4 rv1 = *(const ushort4*)(r + (size_t)e1.y * DIM + lane * 4);
        ushort4 xv2 = *(const ushort4*)(x + (size_t)e2.x * DIM + lane * 4);
        ushort4 rv2 = *(const ushort4*)(r + (size_t)e2.y * DIM + lane * 4);
        ushort4 xv3 = *(const ushort4*)(x + (size_t)e3.x * DIM + lane * 4);
        ushort4 rv3 = *(const ushort4*)(r + (size_t)e3.y * DIM + lane * 4);
        a0 += (b2f(xv0.x) - b2f(rv0.x)) + (b2f(xv2.x) - b2f(rv2.x));
        a1 += (b2f(xv0.y) - b2f(rv0.y)) + (b2f(xv2.y) - b2f(rv2.y));
        a2 += (b2f(xv0.z) - b2f(rv0.z)) + (b2f(xv2.z) - b2f(rv2.z));
        a3 += (b2f(xv0.w) - b2f(rv0.w)) + (b2f(xv2.w) - b2f(rv2.w));
        c0 += (b2f(xv1.x) - b2f(rv1.x)) + w3 * (b2f(xv3.x) - b2f(rv3.x));
        c1 += (b2f(xv1.y) - b2f(rv1.y)) + w3 * (b2f(xv3.y) - b2f(rv3.y));
        c2 += (b2f(xv1.z) - b2f(rv1.z)) + w3 * (b2f(xv3.z) - b2f(rv3.z));
        c3 += (b2f(xv1.w) - b2f(rv1.w)) + w3 * (b2f(xv3.w) - b2f(rv3.w));
        i = (deg >= 4) ? 4 : 3;
    }
    for (; i + 2 <= deg; i += 2) {
        int2 e0 = epair[start + i];
        int2 e1 = epair[start + i + 1];
        ushort4 xv0 = *(const ushort4*)(x + (size_t)e0.x * DIM + lane * 4);
        ushort4 rv0 = *(const ushort4*)(r + (size_t)e0.y * DIM + lane * 4);
        ushort4 xv1 = *(const ushort4*)(x + (size_t)e1.x * DIM + lane * 4);
        ushort4 rv1 = *(const ushort4*)(r + (size_t)e1.y * DIM + lane * 4);
        a0 += b2f(xv0.x) - b2f(rv0.x);
        a1 += b2f(xv0.y) - b2f(rv0.y);
        a2 += b2f(xv0.z) - b2f(rv0.z);
        a3 += b2f(xv0.w) - b2f(rv0.w);
        c0 += b2f(xv1.x) - b2f(rv1.x);
        c1 += b2f(xv1.y) - b2f(rv1.y);
        c2 += b2f(xv1.z) - b2f(rv1.z);
        c3 += b2f(xv1.w) - b2f(rv1.w);
    }
    if (i < deg) {
        int2 e = epair[start + i];
        ushort4 xv = *(const ushort4*)(x + (size_t)e.x * DIM + lane * 4);
        ushort4 rv = *(const ushort4*)(r + (size_t)e.y * DIM + lane * 4);
        a0 += b2f(xv.x) - b2f(rv.x);
        a1 += b2f(xv.y) - b2f(rv.y);
        a2 += b2f(xv.z) - b2f(rv.z);
        a3 += b2f(xv.w) - b2f(rv.w);
    }
    float sc = 1.0f / fmaxf((float)deg, 1.0f);
    ushort4 o;
    o.x = f2b((a0 + c0) * sc);
    o.y = f2b((a1 + c1) * sc);
    o.z = f2b((a2 + c2) * sc);
    o.w = f2b((a3 + c3) * sc);
    *(ushort4*)(agg + (size_t)wid * DIM + lane * 4) = o;
}

// ---------------------------------------------------------------------------
// r_out = r_in @ w   fp32 (+ optional bf16 copy), tiny (rows=1000)
// ---------------------------------------------------------------------------
__global__ void rgemm_kernel(const float* __restrict__ r, const float* __restrict__ w,
                             float* __restrict__ out, unsigned short* __restrict__ outb,
                             int rows) {
    int g = blockIdx.x * 256 + threadIdx.x;
    if (g >= rows * DIM) return;
    int i = g / DIM, j = g - i * DIM;
    float acc = 0.f;
    for (int k = 0; k < DIM; ++k) acc += r[i * DIM + k] * w[k * DIM + j];
    out[g] = acc;
    if (outb) outb[g] = f2b(acc);
}

// ---------------------------------------------------------------------------
// MFMA layer v10 (R16, best measured): 16x16x32, k-major conflict-free LDS,
// double-buffered global_load_lds staging (no reg round-trip).
// ---------------------------------------------------------------------------
#define LOAD_A1(g, slot) do {                                                   \
    const unsigned short* Ap_ = Aseg[(g) / 7];                                  \
    apf[slot] = *(const bf16x8*)(Ap_ + (size_t)arow * 200 + ((g) % 7) * 32 + lq * 8); \
} while (0)

#define STAGE_GLD(s, b) do {                                                     \
    _Pragma("unroll")                                                            \
    for (int it = 0; it < 4; ++it) {                                             \
        int u = tid + it * 256;                                                  \
        int slot = u / 448;                                                      \
        int rem  = u - slot * 448;                                               \
        int ui   = rem / 112, col = rem - ui * 112;                              \
        int g2   = (s) * 2 + slot;                                               \
        if (u < 896 && g2 < 21) {                                                \
            int sg = g2 / 7, kc = g2 % 7;                                        \
            const unsigned short* gp = WTK +                                     \
                ((size_t)(sg * 28 + kc * 4 + ui) * 224 + colbase + col) * 8;     \
            __builtin_amdgcn_global_load_lds(                                    \
                (const GLOBAL_AS unsigned int*)(const void*)gp,                  \
                (LDS_AS unsigned int*)(void*)(&Wl[(b)][u * 8]), 16, 0, 0);       \
        }                                                                        \
    }                                                                            \
} while (0)

__global__ __launch_bounds__(256, 4) void layer_mfma_kernel(
        const unsigned short* __restrict__ aggI, const unsigned short* __restrict__ aggO,
        const unsigned short* __restrict__ xin, const unsigned short* __restrict__ WTK,
        const float* __restrict__ lv, const float* __restrict__ bias,
        unsigned short* __restrict__ out, int nwg) {
    __shared__ unsigned short Wl[2][8 * 112 * 8];     // 2 x 14,336 B
    const int bid = blockIdx.x;
    const int q = nwg >> 3, rr = nwg & 7;
    const int xcd = bid & 7, idx = bid >> 3;
    const int L = (xcd < rr ? xcd * (q + 1) : rr * (q + 1) + (xcd - rr) * q) + idx;
    const int rowblk  = L >> 1;
    const int colbase = (L & 1) * 112;

    const int tid  = threadIdx.x;
    const int wm   = tid >> 6;
    const int lane = tid & 63;
    const int lr   = lane & 15;
    const int lq   = lane >> 4;
    const int row0 = rowblk * 64;
    const int arow = row0 + wm * 16 + lr;

    const unsigned short* const Aseg[3] = { aggI, aggO, xin };

    f32x4 acc[7];
#pragma unroll
    for (int n = 0; n < 7; ++n) acc[n] = (f32x4){0.f, 0.f, 0.f, 0.f};

    bf16x8 apf[4];                        // rotating A prefetch, depth 3
    LOAD_A1(0, 0);
    LOAD_A1(1, 1);
    LOAD_A1(2, 2);

    // prologue: async-stage slice 0 into buf 0 (vmcnt drained at barrier)
    STAGE_GLD(0, 0);
    __syncthreads();

#pragma unroll
    for (int p = 0; p < 11; ++p) {
        if (p < 10) STAGE_GLD(p + 1, (p + 1) & 1);
        const int NC = (p < 10) ? 2 : 1;
#pragma unroll
        for (int cc = 0; cc < NC; ++cc) {
            const int g = p * 2 + cc;                 // literal after unroll
            if (g + 3 < 21) LOAD_A1(g + 3, (g + 3) & 3);
            __builtin_amdgcn_s_setprio(1);
#pragma unroll
            for (int n = 0; n < 7; ++n) {
                bf16x8 b = *(const bf16x8*)(&Wl[p & 1][((cc * 4 + lq) * 112 + n * 16 + lr) * 8]);
                acc[n] = __builtin_amdgcn_mfma_f32_16x16x32_bf16(apf[g & 3], b, acc[n], 0, 0, 0);
            }
            __builtin_amdgcn_s_setprio(0);
        }
        __syncthreads();                  // drains vmcnt: slice p+1 landed
    }

    {
        int rbase = row0 + wm * 16 + lq * 4;
#pragma unroll
        for (int n = 0; n < 7; ++n) {
            int col = colbase + n * 16 + lr;
            if (col < 200) {
                float lvc = lv[col], bc = bias[col];
#pragma unroll
                for (int r2 = 0; r2 < 4; ++r2) {
                    int row = rbase + r2;
                    if (row < N_ENT) {
                        float v = (acc[n][r2] - lvc) * (1.0f / 3.0f) + bc;
                        out[(size_t)row * 200 + col] = f2b(fast_tanh(v));
                    }
                }
            }
        }
    }
}

// ---------------------------------------------------------------------------
// im2col fused with BN0 image build: IM[b*196+p][64] directly from x/r.
// ---------------------------------------------------------------------------
__global__ void im2col_kernel(const unsigned short* __restrict__ x, const float* __restrict__ r,
                              const int* __restrict__ sub, const int* __restrict__ rel,
                              const float* __restrict__ bn0g, const float* __restrict__ bn0b,
                              unsigned short* __restrict__ IM) {
    int g = blockIdx.x * 256 + threadIdx.x;
    if (g >= 50176 * 64) return;
    int row = g >> 6, k = g & 63;
    int b = row / 196, p = row - b * 196;
    int h = p / 14, w = p - h * 14;
    unsigned short o = 0;
    if (k < 49) {
        int i = k / 7, j = k - i * 7;
        int l = (h + i) * 20 + (w + j);
        int d = l >> 1;
        float v = (l & 1) ? r[(size_t)rel[b] * DIM + d] : b2f(x[(size_t)sub[b] * DIM + d]);
        float s0 = bn0g[0] * rsqrtf(1.0f + EPS_BN);
        o = f2b(v * s0 + bn0b[0]);
    }
    IM[g] = o;
}

// ---------------------------------------------------------------------------
// conv as MFMA: [50176 x 64] @ [64 x 200(pad 208)], zero-LDS/zero-barrier.
// ---------------------------------------------------------------------------
__global__ __launch_bounds__(256) void conv_mfma_kernel(
        const unsigned short* __restrict__ IM, const unsigned short* __restrict__ CWT,
        const float* __restrict__ cb, const float* __restrict__ bn1g,
        const float* __restrict__ bn1b, unsigned short* __restrict__ CO_B) {
    const int tid  = threadIdx.x;
    const int row0 = blockIdx.x * 128;
    const int wave = tid >> 6;
    const int lane = tid & 63;
    const int lr   = lane & 15;
    const int lq   = lane >> 4;
    const int arow = row0 + wave * 32 + lr;

    f32x4 acc[2][13];
#pragma unroll
    for (int m = 0; m < 2; ++m)
#pragma unroll
        for (int n = 0; n < 13; ++n) acc[m][n] = (f32x4){0.f, 0.f, 0.f, 0.f};

#pragma unroll
    for (int c = 0; c < 2; ++c) {
        const int k = c * 32 + lq * 8;
        bf16x8 a0 = *(const bf16x8*)(IM + (size_t)arow * 64 + k);
        bf16x8 a1 = *(const bf16x8*)(IM + (size_t)(arow + 16) * 64 + k);
#pragma unroll
        for (int n = 0; n < 13; ++n) {
            bf16x8 b = *(const bf16x8*)(CWT + (size_t)(n * 16 + lr) * 64 + k);
            acc[0][n] = __builtin_amdgcn_mfma_f32_16x16x32_bf16(a0, b, acc[0][n], 0, 0, 0);
            acc[1][n] = __builtin_amdgcn_mfma_f32_16x16x32_bf16(a1, b, acc[1][n], 0, 0, 0);
        }
    }

#pragma unroll
    for (int m = 0; m < 2; ++m) {
        int grow_base = row0 + wave * 32 + m * 16 + lq * 4;
#pragma unroll
        for (int n = 0; n < 13; ++n) {
            int col = n * 16 + lr;          // filter
            if (col < 200) {
                float s1 = bn1g[col] * rsqrtf(1.0f + EPS_BN);
                float t1 = bn1b[col];
                float cbf = cb[col];
#pragma unroll
                for (int r = 0; r < 4; ++r) {
                    int grow = grow_base + r;          // b*196+p, always < 50176
                    int b = grow / 196, p = grow - b * 196;
                    float v = fmaxf((acc[m][n][r] + cbf) * s1 + t1, 0.f);
                    CO_B[(size_t)b * FLATK + col * 196 + p] = f2b(v);
                }
            }
        }
    }
}

// ---------------------------------------------------------------------------
// fc as MFMA split-K: [256 x 39200] @ [39200 x 208], 175 k-chunks x 4 m-blocks.
// ---------------------------------------------------------------------------
__global__ __launch_bounds__(256) void fc_mfma_kernel(
        const unsigned short* __restrict__ CO_B, const unsigned short* __restrict__ FWT,
        float* __restrict__ partials) {
    const int tid  = threadIdx.x;
    const int kc   = blockIdx.x >> 2;
    const int mb   = blockIdx.x & 3;
    const int wave = tid >> 6;
    const int lane = tid & 63;
    const int lr   = lane & 15;
    const int lq   = lane >> 4;
    const int m0   = mb * 64 + wave * 16;

    f32x4 acc[13];
#pragma unroll
    for (int n = 0; n < 13; ++n) acc[n] = (f32x4){0.f, 0.f, 0.f, 0.f};

#pragma unroll
    for (int s = 0; s < 7; ++s) {
        const int k = kc * FC_KLEN + s * 32 + lq * 8;
        bf16x8 a = *(const bf16x8*)(CO_B + (size_t)(m0 + lr) * FLATK + k);
#pragma unroll
        for (int n = 0; n < 13; ++n) {
            bf16x8 b = *(const bf16x8*)(FWT + (size_t)(n * 16 + lr) * FLATK + k);
            acc[n] = __builtin_amdgcn_mfma_f32_16x16x32_bf16(a, b, acc[n], 0, 0, 0);
        }
    }

    float* slab = partials + (size_t)kc * (BB * 208);
#pragma unroll
    for (int n = 0; n < 13; ++n) {
        int col = n * 16 + lr;
#pragma unroll
        for (int r = 0; r < 4; ++r) {
            int row = m0 + lq * 4 + r;
            slab[(size_t)row * 208 + col] = acc[n][r];
        }
    }
}

// hb16[b][j=224] = relu((sum_kc partial + fc_b)*bn2s+bn2b) bf16, pad j>=200
__global__ void fc_reduce_kernel(const float* __restrict__ partials,
                                 const float* __restrict__ fcb,
                                 const float* __restrict__ g2, const float* __restrict__ b2v,
                                 unsigned short* __restrict__ hb) {
    int g = blockIdx.x * 256 + threadIdx.x;
    if (g >= BB * 224) return;
    int b = g / 224, j = g - b * 224;
    unsigned short o = 0;
    if (j < 200) {
        float s = 0.f;
        const float* p = partials + (size_t)b * 208 + j;
#pragma unroll 5
        for (int c = 0; c < FC_KC; ++c)
            s += p[(size_t)c * (BB * 208)];
        float v = (s + fcb[j]) * (g2[j] * rsqrtf(1.0f + EPS_BN)) + b2v[j];
        o = f2b(fmaxf(v, 0.f));
    }
    hb[g] = o;
}

// ---------------------------------------------------------------------------
// logits MFMA v2: D[b][ent] = sigmoid(h[b]·x[ent] + eb[ent]).
// ---------------------------------------------------------------------------
#define LOAD_HB(g, buf) do {                                                    \
    const unsigned short* base_ = hb + (size_t)brow * 224 + (g) * 32 + lq * 8;  \
    buf[0] = *(const bf16x8*)(base_);                                           \
    buf[1] = *(const bf16x8*)(base_ + 16 * 224);                                \
} while (0)

__global__ __launch_bounds__(512, 2) void logits_mfma_kernel(
        const unsigned short* __restrict__ x, const unsigned short* __restrict__ hb,
        const float* __restrict__ eb, float* __restrict__ out, int nwg) {
    __shared__ unsigned short Xl[112 * 136];          // 30,464 B
    const int bid = blockIdx.x;
    const int q = nwg >> 3, rr = nwg & 7;
    const int xcd = bid & 7, idx = bid >> 3;
    const int nb = (xcd < rr ? xcd * (q + 1) : rr * (q + 1) + (xcd - rr) * q) + idx;
    const int ent0 = nb * 112;

    const int tid  = threadIdx.x;
    const int wave = tid >> 6;
    const int mh   = wave >> 2;          // batch half (0/1)
    const int wm   = wave & 3;           // 32-row group
    const int lane = tid & 63;
    const int lr   = lane & 15;
    const int lq   = lane >> 4;
    const int brow = mh * 128 + wm * 32 + lr;

    f32x4 acc[2][7];
#pragma unroll
    for (int m = 0; m < 2; ++m)
#pragma unroll
        for (int n = 0; n < 7; ++n) acc[m][n] = (f32x4){0.f, 0.f, 0.f, 0.f};

    bf16x8 apf[3][2];                     // rotating A prefetch, depth 2
    LOAD_HB(0, apf[0]);
    LOAD_HB(1, apf[1]);

#pragma unroll
    for (int ph = 0; ph < 2; ++ph) {
        if (ph) __syncthreads();
        if (ph == 0) {
            // stage k 0..127: 112 rows x 16 int4 units (contiguous per row)
#pragma unroll
            for (int it = 0; it < 4; ++it) {
                int u = tid + it * 512;
                if (u < 1792) {
                    int row = u >> 4, c = u & 15;
                    int ent = ent0 + row;
                    int4 v = make_int4(0, 0, 0, 0);
                    if (ent < N_ENT)
                        v = *(const int4*)(x + (size_t)ent * 200 + c * 8);
                    *(int4*)(&Xl[row * 136 + c * 8]) = v;
                }
            }
        } else {
            // stage k 128..223: units 16..27 (real to unit 24, then zeros)
            for (int u = tid; u < 1344; u += 512) {
                int row = u / 12, c = u - row * 12;
                int gu = 16 + c;
                int ent = ent0 + row;
                int4 v = make_int4(0, 0, 0, 0);
                if (ent < N_ENT && gu < 25)
                    v = *(const int4*)(x + (size_t)ent * 200 + gu * 8);
                *(int4*)(&Xl[row * 136 + c * 8]) = v;
            }
        }
        __syncthreads();
        const int NC = (ph == 0) ? 4 : 3;
#pragma unroll
        for (int cc = 0; cc < NC; ++cc) {
            const int g = (ph ? 4 : 0) + cc;
            if (g + 2 < 7) LOAD_HB(g + 2, apf[(g + 2) % 3]);
#pragma unroll
            for (int n = 0; n < 7; ++n) {
                bf16x8 b = *(const bf16x8*)(&Xl[(n * 16 + lr) * 136 + cc * 32 + lq * 8]);
                acc[0][n] = __builtin_amdgcn_mfma_f32_16x16x32_bf16(apf[g % 3][0], b, acc[0][n], 0, 0, 0);
                acc[1][n] = __builtin_amdgcn_mfma_f32_16x16x32_bf16(apf[g % 3][1], b, acc[1][n], 0, 0, 0);
            }
        }
    }

#pragma unroll
    for (int m = 0; m < 2; ++m) {
        int b_base = mh * 128 + wm * 32 + m * 16 + lq * 4;
#pragma unroll
        for (int n = 0; n < 7; ++n) {
            int ent = ent0 + n * 16 + lr;
            if (ent < N_ENT) {
                float bias = eb[ent];
#pragma unroll
                for (int r = 0; r < 4; ++r) {
                    float v = acc[m][n][r] + bias;
                    out[(size_t)(b_base + r) * N_ENT + ent] = 1.0f / (1.0f + __expf(-v));
                }
            }
        }
    }
}

// ---------------------------------------------------------------------------
extern "C" void kernel_launch(void* const* d_in, const int* in_sizes, int n_in,
                              void* d_out, int out_size, void* d_ws, size_t ws_size,
                              hipStream_t stream) {
    const int*   sub        = (const int*)  d_in[0];
    const int*   rel        = (const int*)  d_in[1];
    const int*   edge_index = (const int*)  d_in[2];
    const int*   edge_type  = (const int*)  d_in[3];
    const float* init_embed = (const float*)d_in[4];
    const float* init_rel   = (const float*)d_in[5];
    const float* loop_rel1  = (const float*)d_in[6];
    const float* loop_rel2  = (const float*)d_in[7];
    const float* w_in1      = (const float*)d_in[8];
    const float* w_out1     = (const float*)d_in[9];
    const float* w_loop1    = (const float*)d_in[10];
    const float* w_rel1     = (const float*)d_in[11];
    const float* b1         = (const float*)d_in[12];
    const float* w_in2      = (const float*)d_in[13];
    const float* w_out2     = (const float*)d_in[14];
    const float* w_loop2    = (const float*)d_in[15];
    const float* w_rel2     = (const float*)d_in[16];
    const float* b2         = (const float*)d_in[17];
    const float* conv_w     = (const float*)d_in[18];
    const float* conv_b     = (const float*)d_in[19];
    const float* bn0_g      = (const float*)d_in[20];
    const float* bn0_b      = (const float*)d_in[21];
    const float* bn1_g      = (const float*)d_in[22];
    const float* bn1_b      = (const float*)d_in[23];
    const float* bn2_g      = (const float*)d_in[24];
    const float* bn2_b      = (const float*)d_in[25];
    const float* fc_w       = (const float*)d_in[26];
    const float* fc_b       = (const float*)d_in[27];
    const float* ent_bias   = (const float*)d_in[28];

    // ---- bf16 region ----
    unsigned short* aggb = (unsigned short*)d_ws;     // 40,000,000
    unsigned short* x0b  = aggb + 40000000;           // 20,000,000 (init; reused as x2b)
    unsigned short* x1b  = x0b  + 20000000;           // 20,000,000
    unsigned short* r0b  = x1b  + 20000000;           //    200,000
    unsigned short* r1b  = r0b  + 200000;             //    200,000
    unsigned short* WTK  = r1b  + 200000;             //    150,528 (3*28*224*8)
    unsigned short* img  = WTK  + 150528;             //    102,400 (unused, kept for layout)
    unsigned short* IM   = img  + 102400;             //  3,211,264 (50176*64)
    unsigned short* CWT  = IM   + 3211264;            //     13,312
    unsigned short* CO_B = CWT  + 13312;              // 10,035,200 (256*39200)
    unsigned short* hb16 = CO_B + 10035200;           //     57,344 (256*224)
    unsigned short* FWT  = hb16 + 57344;              //  8,153,600 (208*39200)
    // ---- fp32 region ----
    float* fbase = (float*)(FWT + 8153600);
    float* r1f      = fbase;                          // 200,000
    float* r2f      = r1f  + 200000;                  // 200,000
    float* lv       = r2f  + 200000;                  // 256
    float* partials = lv   + 256;                     // 9,318,400 (175*256*208)

    // CSR ints alias CO_B (last CSR read = gather2, before conv writes CO_B)
    int2* epair    = (int2*)CO_B;                     // 500,000 int2
    int* cnt       = (int*)(epair + E_TOT);           // 200,000
    int* row_start = cnt  + NROWS;                    // 200,000
    int* row_cur   = row_start + NROWS;               // 200,000
    int* blockSum  = row_cur + NROWS;                 // 98

    unsigned short* aggIb = aggb;
    unsigned short* aggOb = aggb + (size_t)N_ENT * DIM;
    unsigned short* x2b   = x0b;

    const int gather_blocks = (NROWS + 3) / 4;
    const int layer_nwg     = ((N_ENT + 63) / 64) * 2;     // 3126 (64-row x 2 col-halves)
    const int logits_nwg    = (N_ENT + 111) / 112;         // 893
    const int cvt_nb1       = (N_ENT * DIM / 4 + 255) / 256;   // 19532
    const int cvt_nb2       = (N_REL2 * DIM / 4 + 255) / 256;  // 196

    // ---- converts (fused) + CSR build ----
    convert2_kernel<<<cvt_nb1 + cvt_nb2, 256, 0, stream>>>(init_embed, x0b, N_ENT * DIM,
                                                           init_rel, r0b, N_REL2 * DIM, cvt_nb1);
    hipMemsetAsync(cnt, 0, (size_t)NROWS * 4, stream);
    hist_kernel<<<(E_TOT + 255) / 256, 256, 0, stream>>>(edge_index, cnt);
    scan1_kernel<<<SNBLK, 256, 0, stream>>>(cnt, row_start, blockSum);
    scan2_kernel<<<1, 128, 0, stream>>>(blockSum);
    scan3_kernel<<<(NROWS + 255) / 256, 256, 0, stream>>>(row_start, row_cur, blockSum);
    fill_kernel<<<(E_TOT + 255) / 256, 256, 0, stream>>>(edge_index, edge_type, row_cur, epair);

    // ---- layer 1 ----
    wstack_lv_kernel<<<589, 256, 0, stream>>>(w_in1, w_out1, w_loop1, loop_rel1, lv, WTK);
    gather_kernel<<<gather_blocks, 256, 0, stream>>>(x0b, r0b, epair, row_start, cnt, aggb);
    layer_mfma_kernel<<<layer_nwg, 256, 0, stream>>>(aggIb, aggOb, x0b, WTK, lv, b1, x1b, layer_nwg);
    rgemm_kernel<<<(N_REL2 * DIM + 255) / 256, 256, 0, stream>>>(init_rel, w_rel1, r1f, r1b, N_REL2);

    // ---- layer 2 ----
    wstack_lv_kernel<<<589, 256, 0, stream>>>(w_in2, w_out2, w_loop2, loop_rel2, lv, WTK);
    gather_kernel<<<gather_blocks, 256, 0, stream>>>(x1b, r1b, epair, row_start, cnt, aggb);
    layer_mfma_kernel<<<layer_nwg, 256, 0, stream>>>(aggIb, aggOb, x1b, WTK, lv, b2, x2b, layer_nwg);
    rgemm_kernel<<<(N_REL2 * DIM + 255) / 256, 256, 0, stream>>>(r1f, w_rel2, r2f,
                                                                 (unsigned short*)nullptr, N_REL2);

    // ---- ConvE ----
    im2col_kernel<<<(50176 * 64 + 255) / 256, 256, 0, stream>>>(x2b, r2f, sub, rel,
                                                                bn0_g, bn0_b, IM);
    fwt_cwt_kernel<<<8575 + 52, 256, 0, stream>>>(fc_w, FWT, conv_w, CWT);
    conv_mfma_kernel<<<50176 / 128, 256, 0, stream>>>(IM, CWT, conv_b, bn1_g, bn1_b, CO_B);
    fc_mfma_kernel<<<FC_KC * 4, 256, 0, stream>>>(CO_B, FWT, partials);
    fc_reduce_kernel<<<(BB * 224 + 255) / 256, 256, 0, stream>>>(partials, fc_b, bn2_g, bn2_b, hb16);

    // ---- logits ----
    logits_mfma_kernel<<<logits_nwg, 512, 0, stream>>>(x2b, hb16, ent_bias, (float*)d_out,
                                                       logits_nwg);
}